// Round 5
// baseline (326.032 us; speedup 1.0000x reference)
//
#include <hip/hip_runtime.h>
#include <hip/hip_bf16.h>
#include <math.h>

#define NPOS 32768      // 32*32*32
#define CCH  128
#define C3   384
#define CF   512

typedef __attribute__((ext_vector_type(8))) short short8;
typedef __attribute__((ext_vector_type(4))) float f32x4;

__device__ inline float bf2f(unsigned short u) {
    union { unsigned int i; float f; } x; x.i = ((unsigned int)u) << 16; return x.f;
}
__device__ inline unsigned short f2bf(float f) {
    union { float f; unsigned int i; } x; x.f = f;
    unsigned int r = x.i + 0x7FFFu + ((x.i >> 16) & 1u);   // round-nearest-even
    return (unsigned short)(r >> 16);
}
__device__ inline float lo_bf(unsigned int u) {
    union { unsigned int i; float f; } x; x.i = u << 16; return x.f;
}
__device__ inline float hi_bf(unsigned int u) {
    union { unsigned int i; float f; } x; x.i = u & 0xffff0000u; return x.f;
}

// ---------------------------------------------------------------------------
// bf16 MFMA GEMM, swapped-operand epilogue (lane holds 4 consecutive cols).
// Tile 128 x (NJ*32), BK=32, 256 thr = 4 waves (2x2), 16x16x32 bf16 MFMA.
//   NORMA: A is fp32 (K=128 ch) normalized by stats during staging
//   NORMRES: residual = normalized fp32 resf (Nout=128 ch) via stats
// ---------------------------------------------------------------------------
template<int NJ, bool NORMA, bool GELU, bool NORMRES, bool WF32, bool WBF>
__global__ __launch_bounds__(256) void gemm_mfma(
    const unsigned short* __restrict__ Abf, const float* __restrict__ Af32,
    const unsigned short* __restrict__ B,
    const float* __restrict__ bias, const float* __restrict__ resf,
    const float* __restrict__ stats,
    float* __restrict__ outf, unsigned short* __restrict__ outb,
    int M, int Nout, int K)
{
    constexpr int NT = NJ * 32;            // n-tile
    constexpr int NT2 = NT / 2;            // per-wave n extent
    __shared__ alignas(16) unsigned short As[128 * 40];
    __shared__ alignas(16) unsigned short Bs[NT * 40];
    __shared__ alignas(16) float mLDS[128];
    __shared__ alignas(16) float rsLDS[128];

    const int tid  = threadIdx.x;
    const int lane = tid & 63;
    const int wave = tid >> 6;
    const int wm = wave & 1, wn = wave >> 1;
    const int row0 = blockIdx.y * 128;
    const int col0 = blockIdx.x * NT;

    if (NORMA || NORMRES) {
        if (tid < 128) {
            const float invN = 1.f / (float)NPOS;
            const float m = stats[tid] * invN;
            const float var = stats[128 + tid] * invN - m * m;
            mLDS[tid] = m;
            rsLDS[tid] = rsqrtf(var + 1e-5f);
        }
        __syncthreads();
    }

    const f32x4 fzero = {0.f, 0.f, 0.f, 0.f};
    f32x4 acc[4][NJ];
    #pragma unroll
    for (int i = 0; i < 4; ++i)
        #pragma unroll
        for (int j = 0; j < NJ; ++j) acc[i][j] = fzero;

    const int lr = lane & 15;
    const int quad = lane >> 4;
    const int lk = quad * 8;

    for (int kt = 0; kt < K; kt += 32) {
        for (int c = tid; c < (128 + NT) * 4; c += 256) {
            const int r = c >> 2;
            const int p = (c & 3) * 8;
            if (r < 128) {
                if (NORMA) {
                    const float4 v0 = *(const float4*)&Af32[(size_t)(row0 + r) * K + kt + p];
                    const float4 v1 = *(const float4*)&Af32[(size_t)(row0 + r) * K + kt + p + 4];
                    ushort4 o0, o1;
                    #pragma unroll
                    for (int e = 0; e < 4; ++e) {
                        const int c0 = kt + p + e, c1 = kt + p + 4 + e;
                        (&o0.x)[e] = f2bf(((&v0.x)[e] - mLDS[c0]) * rsLDS[c0]);
                        (&o1.x)[e] = f2bf(((&v1.x)[e] - mLDS[c1]) * rsLDS[c1]);
                    }
                    *(ushort4*)&As[r * 40 + p]     = o0;
                    *(ushort4*)&As[r * 40 + p + 4] = o1;
                } else {
                    *(uint4*)&As[r * 40 + p] =
                        *(const uint4*)&Abf[(size_t)(row0 + r) * K + kt + p];
                }
            } else {
                const int rb = r - 128;
                *(uint4*)&Bs[rb * 40 + p] =
                    *(const uint4*)&B[(size_t)(col0 + rb) * K + kt + p];
            }
        }
        __syncthreads();
        short8 af[4], bfr[NJ];
        #pragma unroll
        for (int i = 0; i < 4; ++i)
            af[i]  = *(const short8*)&As[(wm * 64 + i * 16 + lr) * 40 + lk];
        #pragma unroll
        for (int j = 0; j < NJ; ++j)
            bfr[j] = *(const short8*)&Bs[(wn * NT2 + j * 16 + lr) * 40 + lk];
        #pragma unroll
        for (int i = 0; i < 4; ++i)
            #pragma unroll
            for (int j = 0; j < NJ; ++j)
                acc[i][j] = __builtin_amdgcn_mfma_f32_16x16x32_bf16(
                                bfr[j], af[i], acc[i][j], 0, 0, 0);
        __syncthreads();
    }

    // Swapped C layout: m = row0+wm*64+i*16+(lane&15), n = col0+wn*NT2+j*16+quad*4+r
    float4 bias4[NJ];
    #pragma unroll
    for (int j = 0; j < NJ; ++j)
        bias4[j] = *(const float4*)&bias[col0 + wn * NT2 + j * 16 + quad * 4];

    #pragma unroll
    for (int i = 0; i < 4; ++i) {
        const int m = row0 + wm * 64 + i * 16 + lr;
        #pragma unroll
        for (int j = 0; j < NJ; ++j) {
            const int n0 = col0 + wn * NT2 + j * 16 + quad * 4;
            float v[4];
            #pragma unroll
            for (int r = 0; r < 4; ++r) {
                v[r] = acc[i][j][r] + (&bias4[j].x)[r];
                if (GELU) {
                    const float g = 0.7978845608028654f *
                        (v[r] + 0.044715f * v[r] * v[r] * v[r]);
                    const float e = __expf(2.f * g);
                    v[r] = v[r] * (e / (e + 1.f));
                }
            }
            if (NORMRES) {
                const float4 rv = *(const float4*)&resf[(size_t)m * Nout + n0];
                const float4 mm = *(const float4*)&mLDS[n0];
                const float4 rs = *(const float4*)&rsLDS[n0];
                #pragma unroll
                for (int r = 0; r < 4; ++r)
                    v[r] += ((&rv.x)[r] - (&mm.x)[r]) * (&rs.x)[r];
            }
            if (WF32) {
                float4 o; o.x = v[0]; o.y = v[1]; o.z = v[2]; o.w = v[3];
                *(float4*)&outf[(size_t)m * Nout + n0] = o;
            }
            if (WBF) {
                ushort4 o;
                o.x = f2bf(v[0]); o.y = f2bf(v[1]); o.z = f2bf(v[2]); o.w = f2bf(v[3]);
                *(ushort4*)&outb[(size_t)m * Nout + n0] = o;
            }
        }
    }
}

// ---------------------------------------------------------------------------
// Tiled neighborhood attention (unchanged from R4)
// ---------------------------------------------------------------------------
__global__ __launch_bounds__(256) void attn_tiled(
    const unsigned short* __restrict__ qkv, const float* __restrict__ rpb,
    unsigned short* __restrict__ out)
{
    __shared__ unsigned int ksu[288 * 8];
    __shared__ unsigned int vsu[288 * 8];
    __shared__ unsigned int qsu[32 * 8];
    __shared__ float logits[32 * 29];
    __shared__ float rpbs[125];

    const int t  = threadIdx.x;
    const int line = ((blockIdx.x & 7) << 7) + (blockIdx.x >> 3);
    const int h  = blockIdx.y;
    const int w0 = line & 31, h0 = line >> 5;
    const int n0 = (h0 << 10) + (w0 << 5);
    const int sh0 = min(max(h0 - 1, 0), 29);
    const int sw0 = min(max(w0 - 1, 0), 29);
    const int rh_off = sh0 - h0 + 2;
    const int rw_off = sw0 - w0 + 2;

    if (t < 64) {
        const int pos = t >> 1, part = t & 1;
        const uint4 raw = *(const uint4*)&qkv[(size_t)(n0 + pos) * C3 + h * 16 + part * 8];
        *(uint4*)&qsu[pos * 8 + part * 4] = raw;
    } else if (t < 192) {
        const int i = t - 64;
        if (i < 125) rpbs[i] = rpb[h * 125 + i];
    }
    for (int c = t; c < 1152; c += 256) {
        const int p = c >> 2, part = c & 3;
        const int ihw = p >> 5, z = p & 31;
        const int ih = (ihw * 11) >> 5;
        const int iw = ihw - 3 * ih;
        const int n = ((sh0 + ih) << 10) + ((sw0 + iw) << 5) + z;
        const uint4 raw = *(const uint4*)&qkv[(size_t)n * C3 + CCH + (part >> 1) * CCH
                                              + h * 16 + (part & 1) * 8];
        unsigned int* d = ((part < 2) ? ksu : vsu) + p * 8 + (part & 1) * 4;
        *(uint4*)d = raw;
    }
    __syncthreads();

    {
        const int q = t >> 3, j = t & 7;
        const int sz = min(max(q - 1, 0), 29);
        const int rz_off = sz - q + 2;
        float qf[16];
        #pragma unroll
        for (int d2 = 0; d2 < 8; ++d2) {
            const unsigned int u = qsu[q * 8 + d2];
            qf[2 * d2] = lo_bf(u); qf[2 * d2 + 1] = hi_bf(u);
        }
        for (int kk = j; kk < 27; kk += 8) {
            const int ihw = kk / 3, dz = kk - 3 * ihw;
            const int ih = ihw / 3,  iw = ihw - 3 * ih;
            const int p = ihw * 32 + sz + dz;
            float a = 0.f;
            #pragma unroll
            for (int d2 = 0; d2 < 8; ++d2) {
                const unsigned int u = ksu[p * 8 + d2];
                a += qf[2 * d2] * lo_bf(u) + qf[2 * d2 + 1] * hi_bf(u);
            }
            const int bidx = ((ih + rh_off) * 5 + (iw + rw_off)) * 5 + (dz + rz_off);
            logits[q * 29 + kk] = a * 0.25f + rpbs[bidx];
        }
    }
    __syncthreads();

    if (t < 32) {
        float mx = -1e30f;
        #pragma unroll
        for (int kk = 0; kk < 27; ++kk) mx = fmaxf(mx, logits[t * 29 + kk]);
        float s = 0.f;
        #pragma unroll
        for (int kk = 0; kk < 27; ++kk) {
            const float e = __expf(logits[t * 29 + kk] - mx);
            logits[t * 29 + kk] = e; s += e;
        }
        const float inv = 1.f / s;
        #pragma unroll
        for (int kk = 0; kk < 27; ++kk) logits[t * 29 + kk] *= inv;
    }
    __syncthreads();

    {
        const int q = t >> 3, d2 = t & 7;
        const int sz = min(max(q - 1, 0), 29);
        float ax = 0.f, ay = 0.f;
        #pragma unroll
        for (int kk = 0; kk < 27; ++kk) {
            const int p = (kk / 3) * 32 + sz + (kk % 3);
            const float w = logits[q * 29 + kk];
            const unsigned int u = vsu[p * 8 + d2];
            ax += w * lo_bf(u); ay += w * hi_bf(u);
        }
        const unsigned int o = ((unsigned int)f2bf(ay) << 16) | (unsigned int)f2bf(ax);
        *(unsigned int*)&out[(size_t)(n0 + q) * CCH + h * 16 + d2 * 2] = o;
    }
}

// ---------------------------------------------------------------------------
// stats v2: 512 blocks x 256 thr, float4 reads, LDS reduce, 64 atomics/block
// ---------------------------------------------------------------------------
__global__ __launch_bounds__(256) void stats_v2(
    const float* __restrict__ a, float* __restrict__ stats)
{
    __shared__ float4 redS[8][32];
    __shared__ float4 redQ[8][32];
    const int tid = threadIdx.x;
    const int c4 = tid & 31;          // float4 group -> channels 4*c4..4*c4+3
    const int r  = tid >> 5;          // 0..7
    const int r0 = blockIdx.x * 64;

    float4 s = {0.f, 0.f, 0.f, 0.f}, q = {0.f, 0.f, 0.f, 0.f};
    #pragma unroll
    for (int k = 0; k < 8; ++k) {
        const float4 v = *(const float4*)&a[(size_t)(r0 + r * 8 + k) * CCH + c4 * 4];
        s.x += v.x; s.y += v.y; s.z += v.z; s.w += v.w;
        q.x += v.x * v.x; q.y += v.y * v.y; q.z += v.z * v.z; q.w += v.w * v.w;
    }
    redS[r][c4] = s; redQ[r][c4] = q;
    __syncthreads();
    if (tid < 32) {
        float4 t = redS[0][tid];
        #pragma unroll
        for (int k = 1; k < 8; ++k) {
            const float4 v = redS[k][tid];
            t.x += v.x; t.y += v.y; t.z += v.z; t.w += v.w;
        }
        atomicAdd(&stats[tid * 4 + 0], t.x);
        atomicAdd(&stats[tid * 4 + 1], t.y);
        atomicAdd(&stats[tid * 4 + 2], t.z);
        atomicAdd(&stats[tid * 4 + 3], t.w);
    } else if (tid < 64) {
        const int c = tid - 32;
        float4 t = redQ[0][c];
        #pragma unroll
        for (int k = 1; k < 8; ++k) {
            const float4 v = redQ[k][c];
            t.x += v.x; t.y += v.y; t.z += v.z; t.w += v.w;
        }
        atomicAdd(&stats[CCH + c * 4 + 0], t.x);
        atomicAdd(&stats[CCH + c * 4 + 1], t.y);
        atomicAdd(&stats[CCH + c * 4 + 2], t.z);
        atomicAdd(&stats[CCH + c * 4 + 3], t.w);
    }
}

// fused: zero stats + convert all four weight matrices fp32->bf16
__global__ __launch_bounds__(256) void prep_kernel(
    const float* __restrict__ wq, const float* __restrict__ wp,
    const float* __restrict__ w1, const float* __restrict__ w2,
    unsigned short* __restrict__ wq_b, unsigned short* __restrict__ wp_b,
    unsigned short* __restrict__ w1_b, unsigned short* __restrict__ w2_b,
    float* __restrict__ stats)
{
    const int i = blockIdx.x * 256 + threadIdx.x;
    if (blockIdx.x == 0) {
        stats[threadIdx.x] = 0.f;
        stats[threadIdx.x + 256] = 0.f;
    }
    const float* src; unsigned short* dst; int off;
    if (i < 12288)      { src = wq; dst = wq_b; off = i; }
    else if (i < 16384) { src = wp; dst = wp_b; off = i - 12288; }
    else if (i < 32768) { src = w1; dst = w1_b; off = i - 16384; }
    else                { src = w2; dst = w2_b; off = i - 32768; }
    const float4 v = ((const float4*)src)[off];
    ushort4 o;
    o.x = f2bf(v.x); o.y = f2bf(v.y); o.z = f2bf(v.z); o.w = f2bf(v.w);
    ((ushort4*)dst)[off] = o;
}

// normalize + transpose (N,C) fp32 -> (C,N) fp32 output
__global__ void norm_transpose_kernel(
    const float* __restrict__ t, const float* __restrict__ stats,
    float* __restrict__ out)
{
    __shared__ float tile[32][33];
    const int n0 = blockIdx.x * 32;
    const int c0 = blockIdx.y * 32;
    const int tx = threadIdx.x;
    const int ty = threadIdx.y;
    for (int i = ty; i < 32; i += 8)
        tile[i][tx] = t[(size_t)(n0 + i) * CCH + c0 + tx];
    __syncthreads();
    const float invN = 1.f / (float)NPOS;
    for (int i = ty; i < 32; i += 8) {
        const int c = c0 + i;
        const float m = stats[c] * invN;
        const float var = stats[CCH + c] * invN - m * m;
        const float rs = rsqrtf(var + 1e-5f);
        out[(size_t)c * NPOS + n0 + tx] = (tile[tx][i] - m) * rs;
    }
}

// transpose x (C,N) fp32 -> (N,C) bf16
__global__ __launch_bounds__(256) void transpose_x_kernel(
    const float* __restrict__ x, unsigned short* __restrict__ xt)
{
    __shared__ float tile[32][33];
    const int n0 = blockIdx.x * 32;
    const int c0 = blockIdx.y * 32;
    const int tx = threadIdx.x & 31;
    const int ty = threadIdx.x >> 5;
    for (int i = ty; i < 32; i += 8)
        tile[i][tx] = x[(size_t)(c0 + i) * NPOS + n0 + tx];
    __syncthreads();
    for (int i = ty; i < 32; i += 8)
        xt[(size_t)(n0 + i) * CCH + c0 + tx] = f2bf(tile[tx][i]);
}

// ---------------------------------------------------------------------------
extern "C" void kernel_launch(void* const* d_in, const int* in_sizes, int n_in,
                              void* d_out, int out_size, void* d_ws, size_t ws_size,
                              hipStream_t stream)
{
    const float* x      = (const float*)d_in[0];   // (128, 32768) = (C, N)
    const float* w_qkv  = (const float*)d_in[1];
    const float* b_qkv  = (const float*)d_in[2];
    const float* rpb    = (const float*)d_in[3];
    const float* w_proj = (const float*)d_in[4];
    const float* b_proj = (const float*)d_in[5];
    const float* w_ffn1 = (const float*)d_in[6];
    const float* b_ffn1 = (const float*)d_in[7];
    const float* w_ffn2 = (const float*)d_in[8];
    const float* b_ffn2 = (const float*)d_in[9];
    float* out = (float*)d_out;

    char* ws = (char*)d_ws;
    unsigned short* xt_bf    = (unsigned short*)(ws + 0);          // 8.39 MB
    unsigned short* qkv_bf   = (unsigned short*)(ws + 8388608);    // 25.2 MB
    unsigned short* ffn1_bf  = (unsigned short*)(ws + 0);          // 33.6 MB (reuse)
    unsigned short* attnO_bf = (unsigned short*)(ws + 33554432);   // 8.39 MB
    float*          x5       = (float*)(ws + 41943040);            // 16.8 MB
    float*          tbuf     = (float*)(ws + 67108864);            // 16.8 MB
    unsigned short* wqkv_bf  = (unsigned short*)(ws + 83886080);
    unsigned short* wproj_bf = (unsigned short*)(ws + 83984384);
    unsigned short* wffn1_bf = (unsigned short*)(ws + 84017152);
    unsigned short* wffn2_bf = (unsigned short*)(ws + 84148224);
    float*          stats    = (float*)(ws + 84279296);            // 512 floats
    float* stats1 = stats;
    float* stats2 = stats + 256;

    // 0) fused prep + transpose-convert x
    prep_kernel<<<192, 256, 0, stream>>>(w_qkv, w_proj, w_ffn1, w_ffn2,
                                         wqkv_bf, wproj_bf, wffn1_bf, wffn2_bf, stats);
    transpose_x_kernel<<<dim3(NPOS / 32, CCH / 32), 256, 0, stream>>>(x, xt_bf);

    // 1) qkv = xt @ w_qkv^T + b_qkv   (bf16 out)
    gemm_mfma<4, false, false, false, false, true>
        <<<dim3(C3 / 128, NPOS / 128), 256, 0, stream>>>(
        xt_bf, nullptr, wqkv_bf, b_qkv, nullptr, nullptr,
        nullptr, qkv_bf, NPOS, C3, CCH);

    // 2) tiled neighborhood attention
    attn_tiled<<<dim3(1024, 8), 256, 0, stream>>>(qkv_bf, rpb, attnO_bf);

    // 3) x5 = attnO @ w_proj^T + b_proj  (fp32 out; 64-wide tiles -> 512 blocks)
    gemm_mfma<2, false, false, false, true, false>
        <<<dim3(CCH / 64, NPOS / 128), 256, 0, stream>>>(
        attnO_bf, nullptr, wproj_bf, b_proj, nullptr, nullptr,
        x5, nullptr, NPOS, CCH, CCH);

    // 4) instance norm #1 stats
    stats_v2<<<NPOS / 64, 256, 0, stream>>>(x5, stats1);

    // 5) ffn1 = gelu(norm(x5) @ w_ffn1^T + b_ffn1)  (norm fused into staging)
    gemm_mfma<4, true, true, false, false, true>
        <<<dim3(CF / 128, NPOS / 128), 256, 0, stream>>>(
        nullptr, x5, wffn1_bf, b_ffn1, nullptr, stats1,
        nullptr, ffn1_bf, NPOS, CF, CCH);

    // 6) t = norm(x5) + ffn1 @ w_ffn2^T + b_ffn2  (norm-residual fused)
    gemm_mfma<2, false, false, true, true, false>
        <<<dim3(CCH / 64, NPOS / 128), 256, 0, stream>>>(
        ffn1_bf, nullptr, wffn2_bf, b_ffn2, x5, stats1,
        tbuf, nullptr, NPOS, CCH, CF);

    // 7) instance norm #2 + transpose to (C,N)
    stats_v2<<<NPOS / 64, 256, 0, stream>>>(tbuf, stats2);
    norm_transpose_kernel<<<dim3(NPOS / 32, CCH / 32), dim3(32, 8), 0, stream>>>(
        tbuf, stats2, out);
}

// Round 6
// 252.561 us; speedup vs baseline: 1.2909x; 1.2909x over previous
//
#include <hip/hip_runtime.h>
#include <hip/hip_bf16.h>
#include <math.h>

#define NPOS 32768      // 32*32*32
#define CCH  128
#define C3   384
#define CF   512

typedef __attribute__((ext_vector_type(8))) short short8;
typedef __attribute__((ext_vector_type(4))) float f32x4;

__device__ inline float bf2f(unsigned short u) {
    union { unsigned int i; float f; } x; x.i = ((unsigned int)u) << 16; return x.f;
}
__device__ inline unsigned short f2bf(float f) {
    union { float f; unsigned int i; } x; x.f = f;
    unsigned int r = x.i + 0x7FFFu + ((x.i >> 16) & 1u);   // round-nearest-even
    return (unsigned short)(r >> 16);
}
__device__ inline float lo_bf(unsigned int u) {
    union { unsigned int i; float f; } x; x.i = u << 16; return x.f;
}
__device__ inline float hi_bf(unsigned int u) {
    union { unsigned int i; float f; } x; x.i = u & 0xffff0000u; return x.f;
}

// ---------------------------------------------------------------------------
// bf16 MFMA GEMM, swapped-operand epilogue (lane holds 4 consecutive cols).
// Tile 128 x (NJ*32), BK=32, 256 thr = 4 waves (2x2), 16x16x32 bf16 MFMA.
//   NORMA: A is fp32 (K=128 ch) normalized by stats during staging
//   NORMRES: residual = normalized fp32 resf (Nout=128 ch) via stats
// ---------------------------------------------------------------------------
template<int NJ, bool NORMA, bool GELU, bool NORMRES, bool WF32, bool WBF>
__global__ __launch_bounds__(256) void gemm_mfma(
    const unsigned short* __restrict__ Abf, const float* __restrict__ Af32,
    const unsigned short* __restrict__ B,
    const float* __restrict__ bias, const float* __restrict__ resf,
    const float* __restrict__ stats,
    float* __restrict__ outf, unsigned short* __restrict__ outb,
    int M, int Nout, int K)
{
    constexpr int NT = NJ * 32;            // n-tile
    constexpr int NT2 = NT / 2;            // per-wave n extent
    __shared__ alignas(16) unsigned short As[128 * 40];
    __shared__ alignas(16) unsigned short Bs[NT * 40];
    __shared__ alignas(16) float mLDS[128];
    __shared__ alignas(16) float rsLDS[128];

    const int tid  = threadIdx.x;
    const int lane = tid & 63;
    const int wave = tid >> 6;
    const int wm = wave & 1, wn = wave >> 1;
    const int row0 = blockIdx.y * 128;
    const int col0 = blockIdx.x * NT;

    if (NORMA || NORMRES) {
        if (tid < 128) {
            const float invN = 1.f / (float)NPOS;
            const float m = stats[tid] * invN;
            const float var = stats[128 + tid] * invN - m * m;
            mLDS[tid] = m;
            rsLDS[tid] = rsqrtf(var + 1e-5f);
        }
        __syncthreads();
    }

    const f32x4 fzero = {0.f, 0.f, 0.f, 0.f};
    f32x4 acc[4][NJ];
    #pragma unroll
    for (int i = 0; i < 4; ++i)
        #pragma unroll
        for (int j = 0; j < NJ; ++j) acc[i][j] = fzero;

    const int lr = lane & 15;
    const int quad = lane >> 4;
    const int lk = quad * 8;

    for (int kt = 0; kt < K; kt += 32) {
        for (int c = tid; c < (128 + NT) * 4; c += 256) {
            const int r = c >> 2;
            const int p = (c & 3) * 8;
            if (r < 128) {
                if (NORMA) {
                    const float4 v0 = *(const float4*)&Af32[(size_t)(row0 + r) * K + kt + p];
                    const float4 v1 = *(const float4*)&Af32[(size_t)(row0 + r) * K + kt + p + 4];
                    ushort4 o0, o1;
                    #pragma unroll
                    for (int e = 0; e < 4; ++e) {
                        const int c0 = kt + p + e, c1 = kt + p + 4 + e;
                        (&o0.x)[e] = f2bf(((&v0.x)[e] - mLDS[c0]) * rsLDS[c0]);
                        (&o1.x)[e] = f2bf(((&v1.x)[e] - mLDS[c1]) * rsLDS[c1]);
                    }
                    *(ushort4*)&As[r * 40 + p]     = o0;
                    *(ushort4*)&As[r * 40 + p + 4] = o1;
                } else {
                    *(uint4*)&As[r * 40 + p] =
                        *(const uint4*)&Abf[(size_t)(row0 + r) * K + kt + p];
                }
            } else {
                const int rb = r - 128;
                *(uint4*)&Bs[rb * 40 + p] =
                    *(const uint4*)&B[(size_t)(col0 + rb) * K + kt + p];
            }
        }
        __syncthreads();
        short8 af[4], bfr[NJ];
        #pragma unroll
        for (int i = 0; i < 4; ++i)
            af[i]  = *(const short8*)&As[(wm * 64 + i * 16 + lr) * 40 + lk];
        #pragma unroll
        for (int j = 0; j < NJ; ++j)
            bfr[j] = *(const short8*)&Bs[(wn * NT2 + j * 16 + lr) * 40 + lk];
        #pragma unroll
        for (int i = 0; i < 4; ++i)
            #pragma unroll
            for (int j = 0; j < NJ; ++j)
                acc[i][j] = __builtin_amdgcn_mfma_f32_16x16x32_bf16(
                                bfr[j], af[i], acc[i][j], 0, 0, 0);
        __syncthreads();
    }

    // Swapped C layout: m = row0+wm*64+i*16+(lane&15), n = col0+wn*NT2+j*16+quad*4+r
    float4 bias4[NJ];
    #pragma unroll
    for (int j = 0; j < NJ; ++j)
        bias4[j] = *(const float4*)&bias[col0 + wn * NT2 + j * 16 + quad * 4];

    #pragma unroll
    for (int i = 0; i < 4; ++i) {
        const int m = row0 + wm * 64 + i * 16 + lr;
        #pragma unroll
        for (int j = 0; j < NJ; ++j) {
            const int n0 = col0 + wn * NT2 + j * 16 + quad * 4;
            float v[4];
            #pragma unroll
            for (int r = 0; r < 4; ++r) {
                v[r] = acc[i][j][r] + (&bias4[j].x)[r];
                if (GELU) {
                    const float g = 0.7978845608028654f *
                        (v[r] + 0.044715f * v[r] * v[r] * v[r]);
                    const float e = __expf(2.f * g);
                    v[r] = v[r] * (e / (e + 1.f));
                }
            }
            if (NORMRES) {
                const float4 rv = *(const float4*)&resf[(size_t)m * Nout + n0];
                const float4 mm = *(const float4*)&mLDS[n0];
                const float4 rs = *(const float4*)&rsLDS[n0];
                #pragma unroll
                for (int r = 0; r < 4; ++r)
                    v[r] += ((&rv.x)[r] - (&mm.x)[r]) * (&rs.x)[r];
            }
            if (WF32) {
                float4 o; o.x = v[0]; o.y = v[1]; o.z = v[2]; o.w = v[3];
                *(float4*)&outf[(size_t)m * Nout + n0] = o;
            }
            if (WBF) {
                ushort4 o;
                o.x = f2bf(v[0]); o.y = f2bf(v[1]); o.z = f2bf(v[2]); o.w = f2bf(v[3]);
                *(ushort4*)&outb[(size_t)m * Nout + n0] = o;
            }
        }
    }
}

// ---------------------------------------------------------------------------
// Tiled neighborhood attention (unchanged)
// ---------------------------------------------------------------------------
__global__ __launch_bounds__(256) void attn_tiled(
    const unsigned short* __restrict__ qkv, const float* __restrict__ rpb,
    unsigned short* __restrict__ out)
{
    __shared__ unsigned int ksu[288 * 8];
    __shared__ unsigned int vsu[288 * 8];
    __shared__ unsigned int qsu[32 * 8];
    __shared__ float logits[32 * 29];
    __shared__ float rpbs[125];

    const int t  = threadIdx.x;
    const int line = ((blockIdx.x & 7) << 7) + (blockIdx.x >> 3);
    const int h  = blockIdx.y;
    const int w0 = line & 31, h0 = line >> 5;
    const int n0 = (h0 << 10) + (w0 << 5);
    const int sh0 = min(max(h0 - 1, 0), 29);
    const int sw0 = min(max(w0 - 1, 0), 29);
    const int rh_off = sh0 - h0 + 2;
    const int rw_off = sw0 - w0 + 2;

    if (t < 64) {
        const int pos = t >> 1, part = t & 1;
        const uint4 raw = *(const uint4*)&qkv[(size_t)(n0 + pos) * C3 + h * 16 + part * 8];
        *(uint4*)&qsu[pos * 8 + part * 4] = raw;
    } else if (t < 192) {
        const int i = t - 64;
        if (i < 125) rpbs[i] = rpb[h * 125 + i];
    }
    for (int c = t; c < 1152; c += 256) {
        const int p = c >> 2, part = c & 3;
        const int ihw = p >> 5, z = p & 31;
        const int ih = (ihw * 11) >> 5;
        const int iw = ihw - 3 * ih;
        const int n = ((sh0 + ih) << 10) + ((sw0 + iw) << 5) + z;
        const uint4 raw = *(const uint4*)&qkv[(size_t)n * C3 + CCH + (part >> 1) * CCH
                                              + h * 16 + (part & 1) * 8];
        unsigned int* d = ((part < 2) ? ksu : vsu) + p * 8 + (part & 1) * 4;
        *(uint4*)d = raw;
    }
    __syncthreads();

    {
        const int q = t >> 3, j = t & 7;
        const int sz = min(max(q - 1, 0), 29);
        const int rz_off = sz - q + 2;
        float qf[16];
        #pragma unroll
        for (int d2 = 0; d2 < 8; ++d2) {
            const unsigned int u = qsu[q * 8 + d2];
            qf[2 * d2] = lo_bf(u); qf[2 * d2 + 1] = hi_bf(u);
        }
        for (int kk = j; kk < 27; kk += 8) {
            const int ihw = kk / 3, dz = kk - 3 * ihw;
            const int ih = ihw / 3,  iw = ihw - 3 * ih;
            const int p = ihw * 32 + sz + dz;
            float a = 0.f;
            #pragma unroll
            for (int d2 = 0; d2 < 8; ++d2) {
                const unsigned int u = ksu[p * 8 + d2];
                a += qf[2 * d2] * lo_bf(u) + qf[2 * d2 + 1] * hi_bf(u);
            }
            const int bidx = ((ih + rh_off) * 5 + (iw + rw_off)) * 5 + (dz + rz_off);
            logits[q * 29 + kk] = a * 0.25f + rpbs[bidx];
        }
    }
    __syncthreads();

    if (t < 32) {
        float mx = -1e30f;
        #pragma unroll
        for (int kk = 0; kk < 27; ++kk) mx = fmaxf(mx, logits[t * 29 + kk]);
        float s = 0.f;
        #pragma unroll
        for (int kk = 0; kk < 27; ++kk) {
            const float e = __expf(logits[t * 29 + kk] - mx);
            logits[t * 29 + kk] = e; s += e;
        }
        const float inv = 1.f / s;
        #pragma unroll
        for (int kk = 0; kk < 27; ++kk) logits[t * 29 + kk] *= inv;
    }
    __syncthreads();

    {
        const int q = t >> 3, d2 = t & 7;
        const int sz = min(max(q - 1, 0), 29);
        float ax = 0.f, ay = 0.f;
        #pragma unroll
        for (int kk = 0; kk < 27; ++kk) {
            const int p = (kk / 3) * 32 + sz + (kk % 3);
            const float w = logits[q * 29 + kk];
            const unsigned int u = vsu[p * 8 + d2];
            ax += w * lo_bf(u); ay += w * hi_bf(u);
        }
        const unsigned int o = ((unsigned int)f2bf(ay) << 16) | (unsigned int)f2bf(ax);
        *(unsigned int*)&out[(size_t)(n0 + q) * CCH + h * 16 + d2 * 2] = o;
    }
}

// ---------------------------------------------------------------------------
// Two-phase channel stats, NO atomics.
// p1: 256 blocks x 256 thr; block b reduces rows [b*128, b*128+128) ->
//     partials[b*256 + {0..127 sum, 128..255 sumsq}]
// p2: 1 block, 256 thr; thread t sums partials[b*256+t] over b -> stats[t]
// ---------------------------------------------------------------------------
__global__ __launch_bounds__(256) void stats_p1(
    const float* __restrict__ a, float* __restrict__ partials)
{
    __shared__ float4 redS[8][32];
    __shared__ float4 redQ[8][32];
    const int tid = threadIdx.x;
    const int c4 = tid & 31;          // channels 4*c4 .. 4*c4+3
    const int rg = tid >> 5;          // 0..7
    const int r0 = blockIdx.x * 128;

    float4 s = {0.f, 0.f, 0.f, 0.f}, q = {0.f, 0.f, 0.f, 0.f};
    #pragma unroll
    for (int k = 0; k < 16; ++k) {
        const float4 v = *(const float4*)&a[(size_t)(r0 + rg * 16 + k) * CCH + c4 * 4];
        s.x += v.x; s.y += v.y; s.z += v.z; s.w += v.w;
        q.x += v.x * v.x; q.y += v.y * v.y; q.z += v.z * v.z; q.w += v.w * v.w;
    }
    redS[rg][c4] = s; redQ[rg][c4] = q;
    __syncthreads();
    if (tid < 32) {
        float4 t = redS[0][tid];
        #pragma unroll
        for (int k = 1; k < 8; ++k) {
            const float4 v = redS[k][tid];
            t.x += v.x; t.y += v.y; t.z += v.z; t.w += v.w;
        }
        *(float4*)&partials[(size_t)blockIdx.x * 256 + tid * 4] = t;
    } else if (tid < 64) {
        const int c = tid - 32;
        float4 t = redQ[0][c];
        #pragma unroll
        for (int k = 1; k < 8; ++k) {
            const float4 v = redQ[k][c];
            t.x += v.x; t.y += v.y; t.z += v.z; t.w += v.w;
        }
        *(float4*)&partials[(size_t)blockIdx.x * 256 + 128 + c * 4] = t;
    }
}

__global__ __launch_bounds__(256) void stats_p2(
    const float* __restrict__ partials, float* __restrict__ stats)
{
    const int t = threadIdx.x;
    float s = 0.f;
    #pragma unroll 8
    for (int b = 0; b < 256; ++b) s += partials[b * 256 + t];
    stats[t] = s;
}

// fused: zero stats + convert all four weight matrices fp32->bf16
__global__ __launch_bounds__(256) void prep_kernel(
    const float* __restrict__ wq, const float* __restrict__ wp,
    const float* __restrict__ w1, const float* __restrict__ w2,
    unsigned short* __restrict__ wq_b, unsigned short* __restrict__ wp_b,
    unsigned short* __restrict__ w1_b, unsigned short* __restrict__ w2_b,
    float* __restrict__ stats)
{
    const int i = blockIdx.x * 256 + threadIdx.x;
    if (blockIdx.x == 0) {
        stats[threadIdx.x] = 0.f;
        stats[threadIdx.x + 256] = 0.f;
    }
    const float* src; unsigned short* dst; int off;
    if (i < 12288)      { src = wq; dst = wq_b; off = i; }
    else if (i < 16384) { src = wp; dst = wp_b; off = i - 12288; }
    else if (i < 32768) { src = w1; dst = w1_b; off = i - 16384; }
    else                { src = w2; dst = w2_b; off = i - 32768; }
    const float4 v = ((const float4*)src)[off];
    ushort4 o;
    o.x = f2bf(v.x); o.y = f2bf(v.y); o.z = f2bf(v.z); o.w = f2bf(v.w);
    ((ushort4*)dst)[off] = o;
}

// normalize + transpose (N,C) fp32 -> (C,N) fp32 output
__global__ void norm_transpose_kernel(
    const float* __restrict__ t, const float* __restrict__ stats,
    float* __restrict__ out)
{
    __shared__ float tile[32][33];
    const int n0 = blockIdx.x * 32;
    const int c0 = blockIdx.y * 32;
    const int tx = threadIdx.x;
    const int ty = threadIdx.y;
    for (int i = ty; i < 32; i += 8)
        tile[i][tx] = t[(size_t)(n0 + i) * CCH + c0 + tx];
    __syncthreads();
    const float invN = 1.f / (float)NPOS;
    for (int i = ty; i < 32; i += 8) {
        const int c = c0 + i;
        const float m = stats[c] * invN;
        const float var = stats[CCH + c] * invN - m * m;
        const float rs = rsqrtf(var + 1e-5f);
        out[(size_t)c * NPOS + n0 + tx] = (tile[tx][i] - m) * rs;
    }
}

// transpose x (C,N) fp32 -> (N,C) bf16
__global__ __launch_bounds__(256) void transpose_x_kernel(
    const float* __restrict__ x, unsigned short* __restrict__ xt)
{
    __shared__ float tile[32][33];
    const int n0 = blockIdx.x * 32;
    const int c0 = blockIdx.y * 32;
    const int tx = threadIdx.x & 31;
    const int ty = threadIdx.x >> 5;
    for (int i = ty; i < 32; i += 8)
        tile[i][tx] = x[(size_t)(c0 + i) * NPOS + n0 + tx];
    __syncthreads();
    for (int i = ty; i < 32; i += 8)
        xt[(size_t)(n0 + i) * CCH + c0 + tx] = f2bf(tile[tx][i]);
}

// ---------------------------------------------------------------------------
extern "C" void kernel_launch(void* const* d_in, const int* in_sizes, int n_in,
                              void* d_out, int out_size, void* d_ws, size_t ws_size,
                              hipStream_t stream)
{
    const float* x      = (const float*)d_in[0];   // (128, 32768) = (C, N)
    const float* w_qkv  = (const float*)d_in[1];
    const float* b_qkv  = (const float*)d_in[2];
    const float* rpb    = (const float*)d_in[3];
    const float* w_proj = (const float*)d_in[4];
    const float* b_proj = (const float*)d_in[5];
    const float* w_ffn1 = (const float*)d_in[6];
    const float* b_ffn1 = (const float*)d_in[7];
    const float* w_ffn2 = (const float*)d_in[8];
    const float* b_ffn2 = (const float*)d_in[9];
    float* out = (float*)d_out;

    char* ws = (char*)d_ws;
    unsigned short* xt_bf    = (unsigned short*)(ws + 0);          // 8.39 MB
    unsigned short* qkv_bf   = (unsigned short*)(ws + 8388608);    // 25.2 MB
    unsigned short* ffn1_bf  = (unsigned short*)(ws + 0);          // 33.6 MB (reuse)
    unsigned short* attnO_bf = (unsigned short*)(ws + 33554432);   // 8.39 MB
    float*          x5       = (float*)(ws + 41943040);            // 16.8 MB
    float*          tbuf     = (float*)(ws + 67108864);            // 16.8 MB
    unsigned short* wqkv_bf  = (unsigned short*)(ws + 83886080);
    unsigned short* wproj_bf = (unsigned short*)(ws + 83984384);
    unsigned short* wffn1_bf = (unsigned short*)(ws + 84017152);
    unsigned short* wffn2_bf = (unsigned short*)(ws + 84148224);
    float*          stats    = (float*)(ws + 84279296);            // 512 floats
    float*          partials = (float*)(ws + 84283392);            // 256 KB
    float* stats1 = stats;
    float* stats2 = stats + 256;

    // 0) fused prep + transpose-convert x
    prep_kernel<<<192, 256, 0, stream>>>(w_qkv, w_proj, w_ffn1, w_ffn2,
                                         wqkv_bf, wproj_bf, wffn1_bf, wffn2_bf, stats);
    transpose_x_kernel<<<dim3(NPOS / 32, CCH / 32), 256, 0, stream>>>(x, xt_bf);

    // 1) qkv = xt @ w_qkv^T + b_qkv   (bf16 out)
    gemm_mfma<4, false, false, false, false, true>
        <<<dim3(C3 / 128, NPOS / 128), 256, 0, stream>>>(
        xt_bf, nullptr, wqkv_bf, b_qkv, nullptr, nullptr,
        nullptr, qkv_bf, NPOS, C3, CCH);

    // 2) tiled neighborhood attention
    attn_tiled<<<dim3(1024, 8), 256, 0, stream>>>(qkv_bf, rpb, attnO_bf);

    // 3) x5 = attnO @ w_proj^T + b_proj  (fp32 out)
    gemm_mfma<2, false, false, false, true, false>
        <<<dim3(CCH / 64, NPOS / 128), 256, 0, stream>>>(
        attnO_bf, nullptr, wproj_bf, b_proj, nullptr, nullptr,
        x5, nullptr, NPOS, CCH, CCH);

    // 4) instance norm #1 stats (two-phase, no atomics)
    stats_p1<<<256, 256, 0, stream>>>(x5, partials);
    stats_p2<<<1, 256, 0, stream>>>(partials, stats1);

    // 5) ffn1 = gelu(norm(x5) @ w_ffn1^T + b_ffn1)  (norm fused into staging)
    gemm_mfma<4, true, true, false, false, true>
        <<<dim3(CF / 128, NPOS / 128), 256, 0, stream>>>(
        nullptr, x5, wffn1_bf, b_ffn1, nullptr, stats1,
        nullptr, ffn1_bf, NPOS, CF, CCH);

    // 6) t = norm(x5) + ffn1 @ w_ffn2^T + b_ffn2  (norm-residual fused)
    gemm_mfma<2, false, false, true, true, false>
        <<<dim3(CCH / 64, NPOS / 128), 256, 0, stream>>>(
        ffn1_bf, nullptr, wffn2_bf, b_ffn2, x5, stats1,
        tbuf, nullptr, NPOS, CCH, CF);

    // 7) instance norm #2 (two-phase) + transpose to (C,N)
    stats_p1<<<256, 256, 0, stream>>>(tbuf, partials);
    stats_p2<<<1, 256, 0, stream>>>(partials, stats2);
    norm_transpose_kernel<<<dim3(NPOS / 32, CCH / 32), dim3(32, 8), 0, stream>>>(
        tbuf, stats2, out);
}

// Round 7
// 241.406 us; speedup vs baseline: 1.3506x; 1.0462x over previous
//
#include <hip/hip_runtime.h>
#include <hip/hip_bf16.h>
#include <math.h>

#define NPOS 32768      // 32*32*32
#define CCH  128
#define C3   384
#define CF   512

typedef __attribute__((ext_vector_type(8))) short short8;
typedef __attribute__((ext_vector_type(4))) float f32x4;

__device__ inline float bf2f(unsigned short u) {
    union { unsigned int i; float f; } x; x.i = ((unsigned int)u) << 16; return x.f;
}
__device__ inline unsigned short f2bf(float f) {
    union { float f; unsigned int i; } x; x.f = f;
    unsigned int r = x.i + 0x7FFFu + ((x.i >> 16) & 1u);   // round-nearest-even
    return (unsigned short)(r >> 16);
}
__device__ inline float lo_bf(unsigned int u) {
    union { unsigned int i; float f; } x; x.i = u << 16; return x.f;
}
__device__ inline float hi_bf(unsigned int u) {
    union { unsigned int i; float f; } x; x.i = u & 0xffff0000u; return x.f;
}

// ---------------------------------------------------------------------------
// bf16 MFMA GEMM, swapped-operand epilogue (lane holds 4 consecutive cols).
// Tile MT x NT, BK=32, 256 thr = 4 waves (WM x WN where WM=MT/64).
// MT=64: waves 1x4 (more blocks -> latency hiding). RES reads bf16 residual.
// ---------------------------------------------------------------------------
template<int MT, int NT, bool GELU, bool RES, bool WF32, bool WBF>
__global__ __launch_bounds__(256) void gemm_mfma(
    const unsigned short* __restrict__ A, const unsigned short* __restrict__ B,
    const float* __restrict__ bias, const unsigned short* __restrict__ res,
    float* __restrict__ outf, unsigned short* __restrict__ outb,
    int M, int Nout, int K)
{
    constexpr int WM  = MT / 64;        // wave rows (1 or 2)
    constexpr int WN  = 4 / WM;         // wave cols
    constexpr int NT2 = NT / WN;        // per-wave n extent
    constexpr int NJW = NT2 / 16;       // n fragments per wave

    __shared__ alignas(16) unsigned short As[MT * 40];
    __shared__ alignas(16) unsigned short Bs[NT * 40];

    const int tid  = threadIdx.x;
    const int lane = tid & 63;
    const int wave = tid >> 6;
    const int wm = wave % WM, wn = wave / WM;
    const int row0 = blockIdx.y * MT;
    const int col0 = blockIdx.x * NT;

    const f32x4 fzero = {0.f, 0.f, 0.f, 0.f};
    f32x4 acc[4][NJW];
    #pragma unroll
    for (int i = 0; i < 4; ++i)
        #pragma unroll
        for (int j = 0; j < NJW; ++j) acc[i][j] = fzero;

    const int lr   = lane & 15;
    const int quad = lane >> 4;
    const int lk   = quad * 8;

    for (int kt = 0; kt < K; kt += 32) {
        #pragma unroll
        for (int c = tid; c < (MT + NT) * 4; c += 256) {
            const int r = c >> 2;
            const int p = (c & 3) * 8;
            if (r < MT) {
                *(uint4*)&As[r * 40 + p] =
                    *(const uint4*)&A[(size_t)(row0 + r) * K + kt + p];
            } else {
                const int rb = r - MT;
                *(uint4*)&Bs[rb * 40 + p] =
                    *(const uint4*)&B[(size_t)(col0 + rb) * K + kt + p];
            }
        }
        __syncthreads();
        short8 af[4], bfr[NJW];
        #pragma unroll
        for (int i = 0; i < 4; ++i)
            af[i]  = *(const short8*)&As[(wm * 64 + i * 16 + lr) * 40 + lk];
        #pragma unroll
        for (int j = 0; j < NJW; ++j)
            bfr[j] = *(const short8*)&Bs[(wn * NT2 + j * 16 + lr) * 40 + lk];
        #pragma unroll
        for (int i = 0; i < 4; ++i)
            #pragma unroll
            for (int j = 0; j < NJW; ++j)
                acc[i][j] = __builtin_amdgcn_mfma_f32_16x16x32_bf16(
                                bfr[j], af[i], acc[i][j], 0, 0, 0);
        __syncthreads();
    }

    // Swapped C layout: m = row0+wm*64+i*16+lr, n = col0+wn*NT2+j*16+quad*4+r
    float4 bias4[NJW];
    #pragma unroll
    for (int j = 0; j < NJW; ++j)
        bias4[j] = *(const float4*)&bias[col0 + wn * NT2 + j * 16 + quad * 4];

    #pragma unroll
    for (int i = 0; i < 4; ++i) {
        const int m = row0 + wm * 64 + i * 16 + lr;
        #pragma unroll
        for (int j = 0; j < NJW; ++j) {
            const int n0 = col0 + wn * NT2 + j * 16 + quad * 4;
            float v[4];
            #pragma unroll
            for (int r = 0; r < 4; ++r) {
                v[r] = acc[i][j][r] + (&bias4[j].x)[r];
                if (GELU) {
                    const float g = 0.7978845608028654f *
                        (v[r] + 0.044715f * v[r] * v[r] * v[r]);
                    const float e = __expf(2.f * g);
                    v[r] = v[r] * (e / (e + 1.f));
                }
            }
            if (RES) {
                const ushort4 rv = *(const ushort4*)&res[(size_t)m * Nout + n0];
                v[0] += bf2f(rv.x); v[1] += bf2f(rv.y);
                v[2] += bf2f(rv.z); v[3] += bf2f(rv.w);
            }
            if (WF32) {
                float4 o; o.x = v[0]; o.y = v[1]; o.z = v[2]; o.w = v[3];
                *(float4*)&outf[(size_t)m * Nout + n0] = o;
            }
            if (WBF) {
                ushort4 o;
                o.x = f2bf(v[0]); o.y = f2bf(v[1]); o.z = f2bf(v[2]); o.w = f2bf(v[3]);
                *(ushort4*)&outb[(size_t)m * Nout + n0] = o;
            }
        }
    }
}

// ---------------------------------------------------------------------------
// Tiled neighborhood attention (unchanged)
// ---------------------------------------------------------------------------
__global__ __launch_bounds__(256) void attn_tiled(
    const unsigned short* __restrict__ qkv, const float* __restrict__ rpb,
    unsigned short* __restrict__ out)
{
    __shared__ unsigned int ksu[288 * 8];
    __shared__ unsigned int vsu[288 * 8];
    __shared__ unsigned int qsu[32 * 8];
    __shared__ float logits[32 * 29];
    __shared__ float rpbs[125];

    const int t  = threadIdx.x;
    const int line = ((blockIdx.x & 7) << 7) + (blockIdx.x >> 3);
    const int h  = blockIdx.y;
    const int w0 = line & 31, h0 = line >> 5;
    const int n0 = (h0 << 10) + (w0 << 5);
    const int sh0 = min(max(h0 - 1, 0), 29);
    const int sw0 = min(max(w0 - 1, 0), 29);
    const int rh_off = sh0 - h0 + 2;
    const int rw_off = sw0 - w0 + 2;

    if (t < 64) {
        const int pos = t >> 1, part = t & 1;
        const uint4 raw = *(const uint4*)&qkv[(size_t)(n0 + pos) * C3 + h * 16 + part * 8];
        *(uint4*)&qsu[pos * 8 + part * 4] = raw;
    } else if (t < 192) {
        const int i = t - 64;
        if (i < 125) rpbs[i] = rpb[h * 125 + i];
    }
    for (int c = t; c < 1152; c += 256) {
        const int p = c >> 2, part = c & 3;
        const int ihw = p >> 5, z = p & 31;
        const int ih = (ihw * 11) >> 5;
        const int iw = ihw - 3 * ih;
        const int n = ((sh0 + ih) << 10) + ((sw0 + iw) << 5) + z;
        const uint4 raw = *(const uint4*)&qkv[(size_t)n * C3 + CCH + (part >> 1) * CCH
                                              + h * 16 + (part & 1) * 8];
        unsigned int* d = ((part < 2) ? ksu : vsu) + p * 8 + (part & 1) * 4;
        *(uint4*)d = raw;
    }
    __syncthreads();

    {
        const int q = t >> 3, j = t & 7;
        const int sz = min(max(q - 1, 0), 29);
        const int rz_off = sz - q + 2;
        float qf[16];
        #pragma unroll
        for (int d2 = 0; d2 < 8; ++d2) {
            const unsigned int u = qsu[q * 8 + d2];
            qf[2 * d2] = lo_bf(u); qf[2 * d2 + 1] = hi_bf(u);
        }
        for (int kk = j; kk < 27; kk += 8) {
            const int ihw = kk / 3, dz = kk - 3 * ihw;
            const int ih = ihw / 3,  iw = ihw - 3 * ih;
            const int p = ihw * 32 + sz + dz;
            float a = 0.f;
            #pragma unroll
            for (int d2 = 0; d2 < 8; ++d2) {
                const unsigned int u = ksu[p * 8 + d2];
                a += qf[2 * d2] * lo_bf(u) + qf[2 * d2 + 1] * hi_bf(u);
            }
            const int bidx = ((ih + rh_off) * 5 + (iw + rw_off)) * 5 + (dz + rz_off);
            logits[q * 29 + kk] = a * 0.25f + rpbs[bidx];
        }
    }
    __syncthreads();

    if (t < 32) {
        float mx = -1e30f;
        #pragma unroll
        for (int kk = 0; kk < 27; ++kk) mx = fmaxf(mx, logits[t * 29 + kk]);
        float s = 0.f;
        #pragma unroll
        for (int kk = 0; kk < 27; ++kk) {
            const float e = __expf(logits[t * 29 + kk] - mx);
            logits[t * 29 + kk] = e; s += e;
        }
        const float inv = 1.f / s;
        #pragma unroll
        for (int kk = 0; kk < 27; ++kk) logits[t * 29 + kk] *= inv;
    }
    __syncthreads();

    {
        const int q = t >> 3, d2 = t & 7;
        const int sz = min(max(q - 1, 0), 29);
        float ax = 0.f, ay = 0.f;
        #pragma unroll
        for (int kk = 0; kk < 27; ++kk) {
            const int p = (kk / 3) * 32 + sz + (kk % 3);
            const float w = logits[q * 29 + kk];
            const unsigned int u = vsu[p * 8 + d2];
            ax += w * lo_bf(u); ay += w * hi_bf(u);
        }
        const unsigned int o = ((unsigned int)f2bf(ay) << 16) | (unsigned int)f2bf(ax);
        *(unsigned int*)&out[(size_t)(n0 + q) * CCH + h * 16 + d2 * 2] = o;
    }
}

// ---------------------------------------------------------------------------
// Two-phase channel stats, NO atomics.
// ---------------------------------------------------------------------------
__global__ __launch_bounds__(256) void stats_p1(
    const float* __restrict__ a, float* __restrict__ partials)
{
    __shared__ float4 redS[8][32];
    __shared__ float4 redQ[8][32];
    const int tid = threadIdx.x;
    const int c4 = tid & 31;
    const int rg = tid >> 5;
    const int r0 = blockIdx.x * 128;

    float4 s = {0.f, 0.f, 0.f, 0.f}, q = {0.f, 0.f, 0.f, 0.f};
    #pragma unroll
    for (int k = 0; k < 16; ++k) {
        const float4 v = *(const float4*)&a[(size_t)(r0 + rg * 16 + k) * CCH + c4 * 4];
        s.x += v.x; s.y += v.y; s.z += v.z; s.w += v.w;
        q.x += v.x * v.x; q.y += v.y * v.y; q.z += v.z * v.z; q.w += v.w * v.w;
    }
    redS[rg][c4] = s; redQ[rg][c4] = q;
    __syncthreads();
    if (tid < 32) {
        float4 t = redS[0][tid];
        #pragma unroll
        for (int k = 1; k < 8; ++k) {
            const float4 v = redS[k][tid];
            t.x += v.x; t.y += v.y; t.z += v.z; t.w += v.w;
        }
        *(float4*)&partials[(size_t)blockIdx.x * 256 + tid * 4] = t;
    } else if (tid < 64) {
        const int c = tid - 32;
        float4 t = redQ[0][c];
        #pragma unroll
        for (int k = 1; k < 8; ++k) {
            const float4 v = redQ[k][c];
            t.x += v.x; t.y += v.y; t.z += v.z; t.w += v.w;
        }
        *(float4*)&partials[(size_t)blockIdx.x * 256 + 128 + c * 4] = t;
    }
}

__global__ __launch_bounds__(256) void stats_p2(
    const float* __restrict__ partials, float* __restrict__ stats)
{
    const int t = threadIdx.x;
    float s = 0.f;
    #pragma unroll 8
    for (int b = 0; b < 256; ++b) s += partials[b * 256 + t];
    stats[t] = s;
}

// normalize (N,128) fp32 -> bf16 (reads stats sums)
__global__ __launch_bounds__(256) void norm_apply_bf(
    const float* __restrict__ a, const float* __restrict__ stats,
    unsigned short* __restrict__ o)
{
    const int i = blockIdx.x * 256 + threadIdx.x;
    const int c0 = (i * 4) & (CCH - 1);
    const float4 v = ((const float4*)a)[i];
    const float invN = 1.f / (float)NPOS;
    ushort4 r;
    #pragma unroll
    for (int j = 0; j < 4; ++j) {
        const int c = c0 + j;
        const float m = stats[c] * invN;
        const float var = stats[CCH + c] * invN - m * m;
        const float rs = rsqrtf(var + 1e-5f);
        (&r.x)[j] = f2bf(((&v.x)[j] - m) * rs);
    }
    *(ushort4*)&o[(size_t)i * 4] = r;
}

// fused: zero stats + convert all four weight matrices fp32->bf16
__global__ __launch_bounds__(256) void prep_kernel(
    const float* __restrict__ wq, const float* __restrict__ wp,
    const float* __restrict__ w1, const float* __restrict__ w2,
    unsigned short* __restrict__ wq_b, unsigned short* __restrict__ wp_b,
    unsigned short* __restrict__ w1_b, unsigned short* __restrict__ w2_b,
    float* __restrict__ stats)
{
    const int i = blockIdx.x * 256 + threadIdx.x;
    if (blockIdx.x == 0) {
        stats[threadIdx.x] = 0.f;
        stats[threadIdx.x + 256] = 0.f;
    }
    const float* src; unsigned short* dst; int off;
    if (i < 12288)      { src = wq; dst = wq_b; off = i; }
    else if (i < 16384) { src = wp; dst = wp_b; off = i - 12288; }
    else if (i < 32768) { src = w1; dst = w1_b; off = i - 16384; }
    else                { src = w2; dst = w2_b; off = i - 32768; }
    const float4 v = ((const float4*)src)[off];
    ushort4 o;
    o.x = f2bf(v.x); o.y = f2bf(v.y); o.z = f2bf(v.z); o.w = f2bf(v.w);
    ((ushort4*)dst)[off] = o;
}

// normalize + transpose (N,C) fp32 -> (C,N) fp32 output
__global__ void norm_transpose_kernel(
    const float* __restrict__ t, const float* __restrict__ stats,
    float* __restrict__ out)
{
    __shared__ float tile[32][33];
    const int n0 = blockIdx.x * 32;
    const int c0 = blockIdx.y * 32;
    const int tx = threadIdx.x;
    const int ty = threadIdx.y;
    for (int i = ty; i < 32; i += 8)
        tile[i][tx] = t[(size_t)(n0 + i) * CCH + c0 + tx];
    __syncthreads();
    const float invN = 1.f / (float)NPOS;
    for (int i = ty; i < 32; i += 8) {
        const int c = c0 + i;
        const float m = stats[c] * invN;
        const float var = stats[CCH + c] * invN - m * m;
        const float rs = rsqrtf(var + 1e-5f);
        out[(size_t)c * NPOS + n0 + tx] = (tile[tx][i] - m) * rs;
    }
}

// transpose x (C,N) fp32 -> (N,C) bf16
__global__ __launch_bounds__(256) void transpose_x_kernel(
    const float* __restrict__ x, unsigned short* __restrict__ xt)
{
    __shared__ float tile[32][33];
    const int n0 = blockIdx.x * 32;
    const int c0 = blockIdx.y * 32;
    const int tx = threadIdx.x & 31;
    const int ty = threadIdx.x >> 5;
    for (int i = ty; i < 32; i += 8)
        tile[i][tx] = x[(size_t)(c0 + i) * NPOS + n0 + tx];
    __syncthreads();
    for (int i = ty; i < 32; i += 8)
        xt[(size_t)(n0 + i) * CCH + c0 + tx] = f2bf(tile[tx][i]);
}

// ---------------------------------------------------------------------------
extern "C" void kernel_launch(void* const* d_in, const int* in_sizes, int n_in,
                              void* d_out, int out_size, void* d_ws, size_t ws_size,
                              hipStream_t stream)
{
    const float* x      = (const float*)d_in[0];   // (128, 32768) = (C, N)
    const float* w_qkv  = (const float*)d_in[1];
    const float* b_qkv  = (const float*)d_in[2];
    const float* rpb    = (const float*)d_in[3];
    const float* w_proj = (const float*)d_in[4];
    const float* b_proj = (const float*)d_in[5];
    const float* w_ffn1 = (const float*)d_in[6];
    const float* b_ffn1 = (const float*)d_in[7];
    const float* w_ffn2 = (const float*)d_in[8];
    const float* b_ffn2 = (const float*)d_in[9];
    float* out = (float*)d_out;

    char* ws = (char*)d_ws;
    unsigned short* xt_bf    = (unsigned short*)(ws + 0);          // 8.39 MB
    unsigned short* qkv_bf   = (unsigned short*)(ws + 8388608);    // 25.2 MB
    unsigned short* ffn1_bf  = (unsigned short*)(ws + 0);          // 33.6 MB (reuse)
    unsigned short* attnO_bf = (unsigned short*)(ws + 33554432);   // 8.39 MB
    float*          x5       = (float*)(ws + 41943040);            // 16.8 MB
    unsigned short* x5n_bf   = (unsigned short*)(ws + 58720256);   // 8.39 MB
    float*          tbuf     = (float*)(ws + 67108864);            // 16.8 MB
    unsigned short* wqkv_bf  = (unsigned short*)(ws + 83886080);
    unsigned short* wproj_bf = (unsigned short*)(ws + 83984384);
    unsigned short* wffn1_bf = (unsigned short*)(ws + 84017152);
    unsigned short* wffn2_bf = (unsigned short*)(ws + 84148224);
    float*          stats    = (float*)(ws + 84279296);            // 512 floats
    float*          partials = (float*)(ws + 84283392);            // 256 KB
    float* stats1 = stats;
    float* stats2 = stats + 256;

    // 0) fused prep + transpose-convert x
    prep_kernel<<<192, 256, 0, stream>>>(w_qkv, w_proj, w_ffn1, w_ffn2,
                                         wqkv_bf, wproj_bf, wffn1_bf, wffn2_bf, stats);
    transpose_x_kernel<<<dim3(NPOS / 32, CCH / 32), 256, 0, stream>>>(x, xt_bf);

    // 1) qkv = xt @ w_qkv^T + b_qkv   (bf16 out; 64x128 tiles, 1536 blocks)
    gemm_mfma<64, 128, false, false, false, true>
        <<<dim3(C3 / 128, NPOS / 64), 256, 0, stream>>>(
        xt_bf, wqkv_bf, b_qkv, nullptr, nullptr, qkv_bf, NPOS, C3, CCH);

    // 2) tiled neighborhood attention
    attn_tiled<<<dim3(1024, 8), 256, 0, stream>>>(qkv_bf, rpb, attnO_bf);

    // 3) x5 = attnO @ w_proj^T + b_proj  (fp32 out; 64x64 tiles, 1024 blocks)
    gemm_mfma<64, 64, false, false, true, false>
        <<<dim3(CCH / 64, NPOS / 64), 256, 0, stream>>>(
        attnO_bf, wproj_bf, b_proj, nullptr, x5, nullptr, NPOS, CCH, CCH);

    // 4) instance norm #1: stats then materialize normalized bf16
    stats_p1<<<256, 256, 0, stream>>>(x5, partials);
    stats_p2<<<1, 256, 0, stream>>>(partials, stats1);
    norm_apply_bf<<<(NPOS * CCH / 4) / 256, 256, 0, stream>>>(x5, stats1, x5n_bf);

    // 5) ffn1 = gelu(x5n @ w_ffn1^T + b_ffn1)  (bf16 out; 2048 blocks)
    gemm_mfma<64, 128, true, false, false, true>
        <<<dim3(CF / 128, NPOS / 64), 256, 0, stream>>>(
        x5n_bf, wffn1_bf, b_ffn1, nullptr, nullptr, ffn1_bf, NPOS, CF, CCH);

    // 6) t = x5n + ffn1 @ w_ffn2^T + b_ffn2  (fp32 out; 1024 blocks, K=512)
    gemm_mfma<64, 64, false, true, true, false>
        <<<dim3(CCH / 64, NPOS / 64), 256, 0, stream>>>(
        ffn1_bf, wffn2_bf, b_ffn2, x5n_bf, tbuf, nullptr, NPOS, CCH, CF);

    // 7) instance norm #2 (two-phase) + transpose to (C,N)
    stats_p1<<<256, 256, 0, stream>>>(tbuf, partials);
    stats_p2<<<1, 256, 0, stream>>>(partials, stats2);
    norm_transpose_kernel<<<dim3(NPOS / 32, CCH / 32), dim3(32, 8), 0, stream>>>(
        tbuf, stats2, out);
}